// Round 9
// baseline (190.883 us; speedup 1.0000x reference)
//
#include <hip/hip_runtime.h>
#include <hip/hip_bf16.h>

#define N_EXPERTS 8
#define T_TOKENS 32768
#define D 512              // D_IN == D_OUT
#define TILE 128           // m-tile and n-tile
#define BK 64
#define NKK (D / BK)       // 8 k-steps
#define MT_MAX 264         // max global m-tiles (sum ceil(cnt_e/128) <= 263)
#define GRID_WG (MT_MAX * 4)     // 1056
#define SCATTER_BLOCKS (T_TOKENS / 256)                  // 128
#define CONVW_BLOCKS ((N_EXPERTS * D * D) / (8 * 256))   // 1024
#define CONVX_BLOCKS ((T_TOKENS * D) / (8 * 256))        // 8192
#define LT_MAX 256
#define GEMM_GRID (N_EXPERTS * LT_MAX * 4)   // fallback grid

typedef __bf16 bf16x8 __attribute__((ext_vector_type(8)));
typedef float  f32x4  __attribute__((ext_vector_type(4)));
typedef unsigned short u16x8 __attribute__((ext_vector_type(8)));

__device__ __forceinline__ unsigned short f2bf(float f) {
    unsigned int u = __float_as_uint(f);
    u += 0x7FFFu + ((u >> 16) & 1u);   // round-to-nearest-even
    return (unsigned short)(u >> 16);
}

__device__ __forceinline__ u16x8 cvt8(float4 a, float4 b) {
    u16x8 o;
    o[0] = f2bf(a.x); o[1] = f2bf(a.y); o[2] = f2bf(a.z); o[3] = f2bf(a.w);
    o[4] = f2bf(b.x); o[5] = f2bf(b.y); o[6] = f2bf(b.z); o[7] = f2bf(b.w);
    return o;
}

__device__ __forceinline__ void gl2lds16(const void* g, void* l) {
    // async global->LDS, 16B/lane; LDS dest = wave-uniform base + lane*16
    __builtin_amdgcn_global_load_lds(
        (const __attribute__((address_space(1))) void*)g,
        (__attribute__((address_space(3))) void*)l, 16, 0, 0);
}

// ---- prep (single launch): scatter token ids into fixed per-expert regions,
// convert W and x to bf16 (streaming), independent block ranges ----
__global__ __launch_bounds__(256) void prep_kernel(
        const int* __restrict__ p, int* __restrict__ fill, int* __restrict__ sorted,
        const float* __restrict__ W, unsigned short* __restrict__ Wb,
        const float* __restrict__ x, unsigned short* __restrict__ xb) {
    int bid = blockIdx.x;
    int tid = threadIdx.x;
    if (bid < SCATTER_BLOCKS) {
        __shared__ int lcount[N_EXPERTS];
        __shared__ int lbase[N_EXPERTS];
        if (tid < N_EXPERTS) lcount[tid] = 0;
        __syncthreads();
        int t = bid * 256 + tid;            // always < T_TOKENS (128*256 == 32768)
        int e = p[t];
        int lrank = atomicAdd(&lcount[e], 1);
        __syncthreads();
        if (tid < N_EXPERTS)
            lbase[tid] = (lcount[tid] > 0) ? atomicAdd(&fill[tid], lcount[tid]) : 0;
        __syncthreads();
        // fill starts at -1 (0xFF memset), atomicAdd returns old => first rank 0
        sorted[e * T_TOKENS + (lbase[e] + 1 + lrank)] = t;
    } else if (bid < SCATTER_BLOCKS + CONVW_BLOCKS) {
        size_t i = ((size_t)(bid - SCATTER_BLOCKS) * 256 + tid) * 8;
        float4 a = *(const float4*)(W + i);
        float4 b = *(const float4*)(W + i + 4);
        *(u16x8*)&Wb[i] = cvt8(a, b);
    } else {
        size_t i = ((size_t)(bid - SCATTER_BLOCKS - CONVW_BLOCKS) * 256 + tid) * 8;
        float4 a = *(const float4*)(x + i);
        float4 b = *(const float4*)(x + i + 4);
        *(u16x8*)&xb[i] = cvt8(a, b);
    }
}

// ---- grouped GEMM: B-only LDS (DMA-staged bytes halved), A direct-to-reg ----
// Wave w owns m-rows [w*32, w*32+32) x all 128 n: A fragments are wave-private
// per-lane gathered bf16 loads from xb at the exact MFMA address
// (xb[tok*D + kk + ks*32 + lq*8]) -- no LDS, no swizzle. Double-buffered one
// FULL K-step ahead. B: gl2lds into XOR-swizzled dbuf LDS (16KB/step).
// Per step issue B(k+1) DMA + A(k+1) loads (8 vmem), then vmcnt(8): all of
// stage(k) complete, next stage stays in flight across both barriers.
// LDS = 33 KB -> 4 blocks/CU (16 waves/CU) for cross-block latency cover.
__global__ __launch_bounds__(256, 4) void moe_gemm_bl(
        const unsigned short* __restrict__ xb, const unsigned short* __restrict__ Wb,
        const float* __restrict__ bias, const int* __restrict__ fill,
        const int* __restrict__ sorted, float* __restrict__ out) {
    __shared__ int s_idx[TILE];
    __shared__ unsigned short sB[2][TILE * BK];   // 32 KB, double-buffered

    int bid = blockIdx.x;
    int w6 = bid >> 3;
    int m = (bid & 7) + (w6 >> 2) * 8;      // global m-tile 0..263
    int bn = w6 & 3;                        // bn-siblings share bid&7 -> same XCD

    int e = 0, lt = 0, tacc = 0, found = 0, cnt_e = 0;
#pragma unroll
    for (int i = 0; i < N_EXPERTS; i++) {
        int c = fill[i] + 1;                // +1 trick (fill started at -1)
        int tiles = (c + TILE - 1) >> 7;
        if (!found && m < tacc + tiles) { e = i; lt = m - tacc; cnt_e = c; found = 1; }
        tacc += tiles;
    }
    if (!found) return;
    int row0 = lt * TILE;

    int tid = threadIdx.x;
    if (tid < TILE) {
        int r = row0 + tid;
        s_idx[tid] = (r < cnt_e) ? sorted[e * T_TOKENS + r] : -1;
    }
    __syncthreads();   // also drains vmcnt -> counting below starts clean

    int wave = tid >> 6, lane = tid & 63;
    int lrow = lane & 15, lq = lane >> 4;
    int srow = lane >> 3, scol = lane & 7, swz = scol ^ srow;   // B-side swizzle

    // A gather bases: frag row = wave*32 + mb*16 + lrow; k-base = lq*8.
    // pad rows (tok<0) read xb row 0 -- products land in discarded C rows.
    const unsigned short* ax[2];
#pragma unroll
    for (int mb = 0; mb < 2; mb++) {
        int tok = s_idx[wave * 32 + mb * 16 + lrow];
        ax[mb] = xb + (size_t)(tok < 0 ? 0 : tok) * D + lq * 8;
    }
    const unsigned short* gB = Wb + (size_t)e * D * D
                             + (size_t)(bn * TILE + wave * 32 + srow) * D + swz * 8;

#define STAGE_B(K, KB) do {                                                   \
    _Pragma("unroll") for (int t = 0; t < 4; t++)                             \
        gl2lds16(gB + (size_t)(t * 8) * D + (K) * BK,                         \
                 &sB[KB][(wave * 32 + t * 8) * BK]);                          \
} while (0)

#define LOAD_A(K, SB) do {                                                    \
    _Pragma("unroll") for (int mb = 0; mb < 2; mb++)                          \
    _Pragma("unroll") for (int ks = 0; ks < 2; ks++)                          \
        ar[SB][mb][ks] = *(const u16x8*)(ax[mb] + (K) * BK + ks * 32);        \
} while (0)

    u16x8 ar[2][2][2];   // [buf][mb][ks], all indices static -> stays in VGPR
    f32x4 acc[2][8];
#pragma unroll
    for (int mb = 0; mb < 2; mb++)
#pragma unroll
        for (int nj = 0; nj < 8; nj++)
            acc[mb][nj] = (f32x4){0.f, 0.f, 0.f, 0.f};

    // prologue: stage(0) = B DMA (4) + A loads (4) in flight
    STAGE_B(0, 0);
    __builtin_amdgcn_sched_barrier(0);
    LOAD_A(0, 0);
    __builtin_amdgcn_sched_barrier(0);

#pragma unroll
    for (int step = 0; step < NKK; step++) {
        // top barrier: prev step's ds_reads retired -> sB[(step+1)&1] free
        asm volatile("s_waitcnt lgkmcnt(0)" ::: "memory");
        __builtin_amdgcn_s_barrier();
        __builtin_amdgcn_sched_barrier(0);
        if (step < NKK - 1) {
            STAGE_B(step + 1, (step + 1) & 1);   // 4 DMAs...
            LOAD_A(step + 1, (step + 1) & 1);    // ...+ 4 reg loads, in flight
            __builtin_amdgcn_sched_barrier(0);
            // wait ONLY for stage(step): 8 younger ops stay outstanding
            asm volatile("s_waitcnt vmcnt(8)" ::: "memory");
        } else {
            asm volatile("s_waitcnt vmcnt(0)" ::: "memory");
        }
        __builtin_amdgcn_s_barrier();            // all waves' B(step) visible
        __builtin_amdgcn_sched_barrier(0);
        const unsigned short* cB = sB[step & 1];
        __builtin_amdgcn_s_setprio(1);
#pragma unroll
        for (int ks = 0; ks < 2; ks++) {
            int cb = (ks * 4 + lq) ^ (lrow & 7);
            bf16x8 bfr[8];
#pragma unroll
            for (int nj = 0; nj < 8; nj++)
                bfr[nj] = *(const bf16x8*)&cB[(16 * nj + lrow) * BK + cb * 8];
#pragma unroll
            for (int mb = 0; mb < 2; mb++) {
                bf16x8 a = *(bf16x8*)&ar[step & 1][mb][ks];
#pragma unroll
                for (int nj = 0; nj < 8; nj++)
                    acc[mb][nj] = __builtin_amdgcn_mfma_f32_16x16x32_bf16(
                        a, bfr[nj], acc[mb][nj], 0, 0, 0);
            }
        }
        __builtin_amdgcn_s_setprio(0);
    }
#undef STAGE_B
#undef LOAD_A

    // ---- coalesced epilogue: fold bias, stage C through LDS (reuse sB as
    // 64x128 f32 = 32 KB), write full 512B row-segments.
    // C/D layout: col = lane&15 (n), row = lq*4 + reg (m).
#pragma unroll
    for (int nj = 0; nj < 8; nj++) {
        float bv = bias[e * D + bn * TILE + 16 * nj + lrow];
#pragma unroll
        for (int mb = 0; mb < 2; mb++)
#pragma unroll
            for (int r = 0; r < 4; r++)
                acc[mb][nj][r] += bv;
    }

    float* ct = (float*)&sB[0][0];   // 32 KB: 64 rows x 128 cols f32
#pragma unroll
    for (int p = 0; p < 2; p++) {
        // MFMA ds_reads done (p=0) / pass-0 ct reads done (p=1)
        asm volatile("s_waitcnt lgkmcnt(0)" ::: "memory");
        __builtin_amdgcn_s_barrier();
        if ((wave >> 1) == p) {      // waves 2p,2p+1 own rows [64p, 64p+64)
#pragma unroll
            for (int mb = 0; mb < 2; mb++)
#pragma unroll
                for (int nj = 0; nj < 8; nj++)
#pragma unroll
                    for (int r = 0; r < 4; r++)
                        ct[((wave & 1) * 32 + 16 * mb + lq * 4 + r) * TILE
                           + 16 * nj + lrow] = acc[mb][nj][r];
        }
        asm volatile("s_waitcnt lgkmcnt(0)" ::: "memory");
        __builtin_amdgcn_s_barrier();
#pragma unroll
        for (int k = 0; k < 8; k++) {
            int u = tid + 256 * k;
            int row = u >> 5, ch = u & 31;
            int tok = s_idx[p * 64 + row];
            f32x4 v = *(const f32x4*)&ct[row * TILE + ch * 4];
            if (tok >= 0)
                *(f32x4*)&out[(size_t)tok * D + bn * TILE + ch * 4] = v;
        }
    }
}

// ---- fallback (tiny ws): fp32-load GEMM, fixed-region decode ----
__global__ __launch_bounds__(256) void moe_gemm_f32(
        const float* __restrict__ x, const float* __restrict__ W,
        const float* __restrict__ bias, const int* __restrict__ fill,
        const int* __restrict__ sorted, float* __restrict__ out) {
    __shared__ int s_idx[TILE];
    __shared__ unsigned short sA[TILE][BK + 8];
    __shared__ unsigned short sB[TILE][BK + 8];

    int bid = blockIdx.x;
    int e = bid & 7;
    int cnt = fill[e] + 1;
    int j = bid >> 3;
    int lt = j >> 2, bn = j & 3;
    int row0 = lt * TILE;
    if (row0 >= cnt) return;

    int tid = threadIdx.x;
    if (tid < TILE) {
        int r = row0 + tid;
        s_idx[tid] = (r < cnt) ? sorted[e * T_TOKENS + r] : -1;
    }
    __syncthreads();

    const float* Wbp = W + (size_t)e * D * D + (size_t)(bn * TILE) * D;

    f32x4 acc[4][4];
#pragma unroll
    for (int i = 0; i < 4; i++)
#pragma unroll
        for (int j2 = 0; j2 < 4; j2++)
            acc[i][j2] = (f32x4){0.f, 0.f, 0.f, 0.f};

    int wave = tid >> 6, lane = tid & 63;
    int wm = (wave >> 1) * 64, wn = (wave & 1) * 64;
    int lrow = lane & 15, lq = lane >> 4;

    for (int kk = 0; kk < D; kk += BK) {
#pragma unroll
        for (int i = 0; i < 8; i++) {
            int flat = tid + i * 256;
            int r = flat >> 4, c = (flat & 15) << 2;
            int tok = s_idx[r];
            float4 v = make_float4(0.f, 0.f, 0.f, 0.f);
            if (tok >= 0) v = *(const float4*)(x + (size_t)tok * D + kk + c);
            ushort4 w4;
            w4.x = f2bf(v.x); w4.y = f2bf(v.y); w4.z = f2bf(v.z); w4.w = f2bf(v.w);
            *(ushort4*)&sA[r][c] = w4;
        }
#pragma unroll
        for (int i = 0; i < 8; i++) {
            int flat = tid + i * 256;
            int r = flat >> 4, c = (flat & 15) << 2;
            float4 v = *(const float4*)(Wbp + (size_t)r * D + kk + c);
            ushort4 w4;
            w4.x = f2bf(v.x); w4.y = f2bf(v.y); w4.z = f2bf(v.z); w4.w = f2bf(v.w);
            *(ushort4*)&sB[r][c] = w4;
        }
        __syncthreads();
#pragma unroll
        for (int ks = 0; ks < 2; ks++) {
            bf16x8 af[4], bfr[4];
#pragma unroll
            for (int i = 0; i < 4; i++)
                af[i] = *(const bf16x8*)&sA[wm + 16 * i + lrow][ks * 32 + lq * 8];
#pragma unroll
            for (int j2 = 0; j2 < 4; j2++)
                bfr[j2] = *(const bf16x8*)&sB[wn + 16 * j2 + lrow][ks * 32 + lq * 8];
#pragma unroll
            for (int i = 0; i < 4; i++)
#pragma unroll
                for (int j2 = 0; j2 < 4; j2++)
                    acc[i][j2] = __builtin_amdgcn_mfma_f32_16x16x32_bf16(
                        af[i], bfr[j2], acc[i][j2], 0, 0, 0);
        }
        __syncthreads();
    }

#pragma unroll
    for (int j2 = 0; j2 < 4; j2++) {
        int ng = bn * TILE + wn + 16 * j2 + lrow;
        float bv = bias[e * D + ng];
#pragma unroll
        for (int i = 0; i < 4; i++) {
#pragma unroll
            for (int r = 0; r < 4; r++) {
                int mrow = wm + 16 * i + lq * 4 + r;
                int tok = s_idx[mrow];
                if (tok >= 0)
                    out[(size_t)tok * D + ng] = acc[i][j2][r] + bv;
            }
        }
    }
}

extern "C" void kernel_launch(void* const* d_in, const int* in_sizes, int n_in,
                              void* d_out, int out_size, void* d_ws, size_t ws_size,
                              hipStream_t stream) {
    const float* x    = (const float*)d_in[0];
    const int*   part = (const int*)d_in[1];
    const float* W    = (const float*)d_in[2];
    const float* b    = (const float*)d_in[3];
    float* out = (float*)d_out;

    const size_t xb_elems     = (size_t)T_TOKENS * D;             // bf16
    const size_t wb_elems     = (size_t)N_EXPERTS * D * D;        // bf16
    const size_t sorted_elems = (size_t)N_EXPERTS * T_TOKENS;     // int
    const size_t fast_bytes   = (xb_elems + wb_elems) * 2 + (sorted_elems + 8) * 4;
    const size_t slow_bytes   = (sorted_elems + 8) * 4;

    if (ws_size >= fast_bytes) {
        unsigned short* xb = (unsigned short*)d_ws;
        unsigned short* Wb = xb + xb_elems;
        int* sorted = (int*)(Wb + wb_elems);
        int* fill   = sorted + sorted_elems;

        hipMemsetAsync(fill, 0xFF, N_EXPERTS * sizeof(int), stream);   // fill = -1
        prep_kernel<<<SCATTER_BLOCKS + CONVW_BLOCKS + CONVX_BLOCKS, 256, 0, stream>>>(
            part, fill, sorted, W, Wb, x, xb);
        moe_gemm_bl<<<GRID_WG, 256, 0, stream>>>(xb, Wb, b, fill, sorted, out);
    } else if (ws_size >= slow_bytes) {
        int* sorted = (int*)d_ws;
        int* fill   = sorted + sorted_elems;

        hipMemsetAsync(fill, 0xFF, N_EXPERTS * sizeof(int), stream);
        prep_kernel<<<SCATTER_BLOCKS, 256, 0, stream>>>(
            part, fill, sorted, (const float*)nullptr, (unsigned short*)nullptr,
            x, (unsigned short*)nullptr);
        moe_gemm_f32<<<GEMM_GRID, 256, 0, stream>>>(x, W, b, fill, sorted, out);
    }
}

// Round 10
// 152.230 us; speedup vs baseline: 1.2539x; 1.2539x over previous
//
#include <hip/hip_runtime.h>
#include <hip/hip_bf16.h>

#define N_EXPERTS 8
#define T_TOKENS 32768
#define D 512              // D_IN == D_OUT
#define TILE 128           // m-tile and n-tile
#define BK 64
#define NKK (D / BK)       // 8 k-steps
#define MT_MAX 264         // max global m-tiles (sum ceil(cnt_e/128) <= 263)
#define GRID_WG (MT_MAX * 4)     // 1056
#define SCATTER_BLOCKS (T_TOKENS / 256)                  // 128
#define CONVW_BLOCKS ((N_EXPERTS * D * D) / (8 * 256))   // 1024
#define CONVX_BLOCKS ((T_TOKENS * D) / (8 * 256))        // 8192
#define LT_MAX 256
#define GEMM_GRID (N_EXPERTS * LT_MAX * 4)   // fallback grid

typedef __bf16 bf16x8 __attribute__((ext_vector_type(8)));
typedef float  f32x4  __attribute__((ext_vector_type(4)));
typedef unsigned short u16x8 __attribute__((ext_vector_type(8)));

__device__ __forceinline__ unsigned short f2bf(float f) {
    unsigned int u = __float_as_uint(f);
    u += 0x7FFFu + ((u >> 16) & 1u);   // round-to-nearest-even
    return (unsigned short)(u >> 16);
}

__device__ __forceinline__ u16x8 cvt8(float4 a, float4 b) {
    u16x8 o;
    o[0] = f2bf(a.x); o[1] = f2bf(a.y); o[2] = f2bf(a.z); o[3] = f2bf(a.w);
    o[4] = f2bf(b.x); o[5] = f2bf(b.y); o[6] = f2bf(b.z); o[7] = f2bf(b.w);
    return o;
}

__device__ __forceinline__ void gl2lds16(const void* g, void* l) {
    // async global->LDS, 16B/lane; LDS dest = wave-uniform base + lane*16
    __builtin_amdgcn_global_load_lds(
        (const __attribute__((address_space(1))) void*)g,
        (__attribute__((address_space(3))) void*)l, 16, 0, 0);
}

// ---- prep (single launch): scatter token ids into fixed per-expert regions,
// convert W and x to bf16 (streaming), independent block ranges ----
__global__ __launch_bounds__(256) void prep_kernel(
        const int* __restrict__ p, int* __restrict__ fill, int* __restrict__ sorted,
        const float* __restrict__ W, unsigned short* __restrict__ Wb,
        const float* __restrict__ x, unsigned short* __restrict__ xb) {
    int bid = blockIdx.x;
    int tid = threadIdx.x;
    if (bid < SCATTER_BLOCKS) {
        __shared__ int lcount[N_EXPERTS];
        __shared__ int lbase[N_EXPERTS];
        if (tid < N_EXPERTS) lcount[tid] = 0;
        __syncthreads();
        int t = bid * 256 + tid;            // always < T_TOKENS (128*256 == 32768)
        int e = p[t];
        int lrank = atomicAdd(&lcount[e], 1);
        __syncthreads();
        if (tid < N_EXPERTS)
            lbase[tid] = (lcount[tid] > 0) ? atomicAdd(&fill[tid], lcount[tid]) : 0;
        __syncthreads();
        // fill starts at -1 (0xFF memset), atomicAdd returns old => first rank 0
        sorted[e * T_TOKENS + (lbase[e] + 1 + lrank)] = t;
    } else if (bid < SCATTER_BLOCKS + CONVW_BLOCKS) {
        size_t i = ((size_t)(bid - SCATTER_BLOCKS) * 256 + tid) * 8;
        float4 a = *(const float4*)(W + i);
        float4 b = *(const float4*)(W + i + 4);
        *(u16x8*)&Wb[i] = cvt8(a, b);
    } else {
        size_t i = ((size_t)(bid - SCATTER_BLOCKS - CONVW_BLOCKS) * 256 + tid) * 8;
        float4 a = *(const float4*)(x + i);
        float4 b = *(const float4*)(x + i + 4);
        *(u16x8*)&xb[i] = cvt8(a, b);
    }
}

// ---- grouped GEMM: split staging paths ----
// A: bf16 xb -> 4 x u16x8 regs/thread (per-lane gather, loaded one FULL step
//    ahead) -> XOR-swizzled ds_write_b128 into SINGLE-buffered sA (16 KB).
//    Write pattern = 2 lanes/bank (free). Halves the DMA-path bytes.
// B: gl2lds into XOR-swizzled DOUBLE-buffered sB (32 KB), issued 1 step ahead.
// Per step: top-bar -> issue B(k+1) DMA -> vmcnt(4) (A(k)+B(k) done; B(k+1)
// in flight) -> ds_write A(k) -> load A(k+1) regs -> lgkm0+bar -> MFMA.
// LDS 48.5 KB -> 3 blocks/CU; launch_bounds(256,3) -> VGPR cap ~168 (NO SPILL
// -- r9 failed on a 128-cap spill, WRITE_SIZE 183MB; watch WRITE_SIZE=64MB).
// Robust to non-unroll: no step-indexed register arrays (rule #20).
__global__ __launch_bounds__(256, 3) void moe_gemm_sp(
        const unsigned short* __restrict__ xb, const unsigned short* __restrict__ Wb,
        const float* __restrict__ bias, const int* __restrict__ fill,
        const int* __restrict__ sorted, float* __restrict__ out) {
    __shared__ int s_idx[TILE];
    __shared__ unsigned short sA[TILE * BK];      // 16 KB, single-buffered
    __shared__ unsigned short sB[2][TILE * BK];   // 32 KB, double-buffered

    int bid = blockIdx.x;
    int w6 = bid >> 3;
    int m = (bid & 7) + (w6 >> 2) * 8;      // global m-tile 0..263
    int bn = w6 & 3;                        // bn-siblings share bid&7 -> same XCD

    int e = 0, lt = 0, tacc = 0, found = 0, cnt_e = 0;
#pragma unroll
    for (int i = 0; i < N_EXPERTS; i++) {
        int c = fill[i] + 1;                // +1 trick (fill started at -1)
        int tiles = (c + TILE - 1) >> 7;
        if (!found && m < tacc + tiles) { e = i; lt = m - tacc; cnt_e = c; found = 1; }
        tacc += tiles;
    }
    if (!found) return;
    int row0 = lt * TILE;

    int tid = threadIdx.x;
    if (tid < TILE) {
        int r = row0 + tid;
        s_idx[tid] = (r < cnt_e) ? sorted[e * T_TOKENS + r] : -1;
    }
    __syncthreads();   // also drains vmcnt -> counting below starts clean

    int wave = tid >> 6, lane = tid & 63;
    int wm = (wave >> 1) * 64, wn = (wave & 1) * 64;
    int lrow = lane & 15, lq = lane >> 4;
    int srow = lane >> 3, scol = lane & 7, swz = scol ^ srow;   // B-side swizzle

    // A staging geometry: thread owns row (tid>>1), k-half (tid&1): 4 x 16B.
    // LDS slot s of row r holds global k-block s^(r&7) (fragment-read XOR).
    int ar_row = tid >> 1, khalf = tid & 1;
    int tokA = s_idx[ar_row];
    const unsigned short* gA = xb + (size_t)(tokA < 0 ? 0 : tokA) * D;
    const unsigned short* aptr[4];
    unsigned short* lA = sA + ar_row * BK + khalf * 32;   // slots khalf*4..+3
#pragma unroll
    for (int j = 0; j < 4; j++)
        aptr[j] = gA + (((khalf * 4 + j) ^ (ar_row & 7)) << 3);

    const unsigned short* gB = Wb + (size_t)e * D * D
                             + (size_t)(bn * TILE + wave * 32 + srow) * D + swz * 8;

#define STAGE_B(K, KB) do {                                                   \
    _Pragma("unroll") for (int t = 0; t < 4; t++)                             \
        gl2lds16(gB + (size_t)(t * 8) * D + (K) * BK,                         \
                 &sB[KB][(wave * 32 + t * 8) * BK]);                          \
} while (0)

#define LOAD_A(K) do {                                                        \
    _Pragma("unroll") for (int j = 0; j < 4; j++)                             \
        pa[j] = *(const u16x8*)(aptr[j] + (K) * BK);                          \
} while (0)

#define WRITE_A() do {                                                        \
    _Pragma("unroll") for (int j = 0; j < 4; j++)                             \
        *(u16x8*)&lA[j * 8] = pa[j];                                          \
} while (0)

    u16x8 pa[4];   // A prefetch regs (single set: consumed then reloaded)
    f32x4 acc[4][4];
#pragma unroll
    for (int i = 0; i < 4; i++)
#pragma unroll
        for (int j2 = 0; j2 < 4; j2++)
            acc[i][j2] = (f32x4){0.f, 0.f, 0.f, 0.f};

    // prologue: queue = [B(0) x4, A(0) x4]
    STAGE_B(0, 0);
    __builtin_amdgcn_sched_barrier(0);
    LOAD_A(0);
    __builtin_amdgcn_sched_barrier(0);

#pragma unroll
    for (int step = 0; step < NKK; step++) {
        // top barrier: all waves' prev ds_reads retired -> sA and sB[(step+1)&1]
        // may be overwritten after this
        asm volatile("s_waitcnt lgkmcnt(0)" ::: "memory");
        __builtin_amdgcn_s_barrier();
        __builtin_amdgcn_sched_barrier(0);
        if (step < NKK - 1) {
            STAGE_B(step + 1, (step + 1) & 1);   // queue [B(k),A(k),B(k+1)]
            __builtin_amdgcn_sched_barrier(0);
            // wait A(k)+B(k) (older) complete; B(k+1) stays in flight
            asm volatile("s_waitcnt vmcnt(4)" ::: "memory");
        } else {
            asm volatile("s_waitcnt vmcnt(0)" ::: "memory");
        }
        WRITE_A();                               // sA <- A(step) from pa
        __builtin_amdgcn_sched_barrier(0);
        if (step < NKK - 1) {
            LOAD_A(step + 1);                    // reload pa (WAR after write)
            __builtin_amdgcn_sched_barrier(0);
        }
        // bottom barrier: own ds_writes done + all waves' stage visible
        asm volatile("s_waitcnt lgkmcnt(0)" ::: "memory");
        __builtin_amdgcn_s_barrier();
        __builtin_amdgcn_sched_barrier(0);
        const unsigned short* cB = sB[step & 1];
        __builtin_amdgcn_s_setprio(1);
#pragma unroll
        for (int ks = 0; ks < 2; ks++) {
            int cb = (ks * 4 + lq) ^ (lrow & 7);
            bf16x8 af[4], bfr[4];
#pragma unroll
            for (int i = 0; i < 4; i++)
                af[i] = *(const bf16x8*)&sA[(wm + 16 * i + lrow) * BK + cb * 8];
#pragma unroll
            for (int j2 = 0; j2 < 4; j2++)
                bfr[j2] = *(const bf16x8*)&cB[(wn + 16 * j2 + lrow) * BK + cb * 8];
#pragma unroll
            for (int i = 0; i < 4; i++)
#pragma unroll
                for (int j2 = 0; j2 < 4; j2++)
                    acc[i][j2] = __builtin_amdgcn_mfma_f32_16x16x32_bf16(
                        af[i], bfr[j2], acc[i][j2], 0, 0, 0);
        }
        __builtin_amdgcn_s_setprio(0);
    }
#undef STAGE_B
#undef LOAD_A
#undef WRITE_A

    // ---- coalesced epilogue: fold bias, stage C through LDS (reuse sB as
    // 64x128 f32 = 32 KB), write full 512B row-segments.
    // C/D layout: col = lane&15 (n), row = lq*4 + reg (m).
#pragma unroll
    for (int j2 = 0; j2 < 4; j2++) {
        float bv = bias[e * D + bn * TILE + wn + 16 * j2 + lrow];
#pragma unroll
        for (int i = 0; i < 4; i++)
#pragma unroll
            for (int r = 0; r < 4; r++)
                acc[i][j2][r] += bv;
    }

    float* ct = (float*)&sB[0][0];   // 32 KB: 64 rows x 128 cols f32
#pragma unroll
    for (int p = 0; p < 2; p++) {
        // MFMA ds_reads done (p=0) / pass-0 ct reads done (p=1)
        asm volatile("s_waitcnt lgkmcnt(0)" ::: "memory");
        __builtin_amdgcn_s_barrier();
        if ((wave >> 1) == p) {      // the 2 waves owning rows [64p, 64p+64)
#pragma unroll
            for (int i = 0; i < 4; i++)
#pragma unroll
                for (int j2 = 0; j2 < 4; j2++)
#pragma unroll
                    for (int r = 0; r < 4; r++)
                        ct[(16 * i + lq * 4 + r) * TILE + wn + 16 * j2 + lrow]
                            = acc[i][j2][r];
        }
        asm volatile("s_waitcnt lgkmcnt(0)" ::: "memory");
        __builtin_amdgcn_s_barrier();
#pragma unroll
        for (int k = 0; k < 8; k++) {
            int u = tid + 256 * k;
            int row = u >> 5, ch = u & 31;
            int tok = s_idx[p * 64 + row];
            f32x4 v = *(const f32x4*)&ct[row * TILE + ch * 4];
            if (tok >= 0)
                *(f32x4*)&out[(size_t)tok * D + bn * TILE + ch * 4] = v;
        }
    }
}

// ---- fallback (tiny ws): fp32-load GEMM, fixed-region decode ----
__global__ __launch_bounds__(256) void moe_gemm_f32(
        const float* __restrict__ x, const float* __restrict__ W,
        const float* __restrict__ bias, const int* __restrict__ fill,
        const int* __restrict__ sorted, float* __restrict__ out) {
    __shared__ int s_idx[TILE];
    __shared__ unsigned short sA[TILE][BK + 8];
    __shared__ unsigned short sB[TILE][BK + 8];

    int bid = blockIdx.x;
    int e = bid & 7;
    int cnt = fill[e] + 1;
    int j = bid >> 3;
    int lt = j >> 2, bn = j & 3;
    int row0 = lt * TILE;
    if (row0 >= cnt) return;

    int tid = threadIdx.x;
    if (tid < TILE) {
        int r = row0 + tid;
        s_idx[tid] = (r < cnt) ? sorted[e * T_TOKENS + r] : -1;
    }
    __syncthreads();

    const float* Wbp = W + (size_t)e * D * D + (size_t)(bn * TILE) * D;

    f32x4 acc[4][4];
#pragma unroll
    for (int i = 0; i < 4; i++)
#pragma unroll
        for (int j2 = 0; j2 < 4; j2++)
            acc[i][j2] = (f32x4){0.f, 0.f, 0.f, 0.f};

    int wave = tid >> 6, lane = tid & 63;
    int wm = (wave >> 1) * 64, wn = (wave & 1) * 64;
    int lrow = lane & 15, lq = lane >> 4;

    for (int kk = 0; kk < D; kk += BK) {
#pragma unroll
        for (int i = 0; i < 8; i++) {
            int flat = tid + i * 256;
            int r = flat >> 4, c = (flat & 15) << 2;
            int tok = s_idx[r];
            float4 v = make_float4(0.f, 0.f, 0.f, 0.f);
            if (tok >= 0) v = *(const float4*)(x + (size_t)tok * D + kk + c);
            ushort4 w4;
            w4.x = f2bf(v.x); w4.y = f2bf(v.y); w4.z = f2bf(v.z); w4.w = f2bf(v.w);
            *(ushort4*)&sA[r][c] = w4;
        }
#pragma unroll
        for (int i = 0; i < 8; i++) {
            int flat = tid + i * 256;
            int r = flat >> 4, c = (flat & 15) << 2;
            float4 v = *(const float4*)(Wbp + (size_t)r * D + kk + c);
            ushort4 w4;
            w4.x = f2bf(v.x); w4.y = f2bf(v.y); w4.z = f2bf(v.z); w4.w = f2bf(v.w);
            *(ushort4*)&sB[r][c] = w4;
        }
        __syncthreads();
#pragma unroll
        for (int ks = 0; ks < 2; ks++) {
            bf16x8 af[4], bfr[4];
#pragma unroll
            for (int i = 0; i < 4; i++)
                af[i] = *(const bf16x8*)&sA[wm + 16 * i + lrow][ks * 32 + lq * 8];
#pragma unroll
            for (int j2 = 0; j2 < 4; j2++)
                bfr[j2] = *(const bf16x8*)&sB[wn + 16 * j2 + lrow][ks * 32 + lq * 8];
#pragma unroll
            for (int i = 0; i < 4; i++)
#pragma unroll
                for (int j2 = 0; j2 < 4; j2++)
                    acc[i][j2] = __builtin_amdgcn_mfma_f32_16x16x32_bf16(
                        af[i], bfr[j2], acc[i][j2], 0, 0, 0);
        }
        __syncthreads();
    }

#pragma unroll
    for (int j2 = 0; j2 < 4; j2++) {
        int ng = bn * TILE + wn + 16 * j2 + lrow;
        float bv = bias[e * D + ng];
#pragma unroll
        for (int i = 0; i < 4; i++) {
#pragma unroll
            for (int r = 0; r < 4; r++) {
                int mrow = wm + 16 * i + lq * 4 + r;
                int tok = s_idx[mrow];
                if (tok >= 0)
                    out[(size_t)tok * D + ng] = acc[i][j2][r] + bv;
            }
        }
    }
}

extern "C" void kernel_launch(void* const* d_in, const int* in_sizes, int n_in,
                              void* d_out, int out_size, void* d_ws, size_t ws_size,
                              hipStream_t stream) {
    const float* x    = (const float*)d_in[0];
    const int*   part = (const int*)d_in[1];
    const float* W    = (const float*)d_in[2];
    const float* b    = (const float*)d_in[3];
    float* out = (float*)d_out;

    const size_t xb_elems     = (size_t)T_TOKENS * D;             // bf16
    const size_t wb_elems     = (size_t)N_EXPERTS * D * D;        // bf16
    const size_t sorted_elems = (size_t)N_EXPERTS * T_TOKENS;     // int
    const size_t fast_bytes   = (xb_elems + wb_elems) * 2 + (sorted_elems + 8) * 4;
    const size_t slow_bytes   = (sorted_elems + 8) * 4;

    if (ws_size >= fast_bytes) {
        unsigned short* xb = (unsigned short*)d_ws;
        unsigned short* Wb = xb + xb_elems;
        int* sorted = (int*)(Wb + wb_elems);
        int* fill   = sorted + sorted_elems;

        hipMemsetAsync(fill, 0xFF, N_EXPERTS * sizeof(int), stream);   // fill = -1
        prep_kernel<<<SCATTER_BLOCKS + CONVW_BLOCKS + CONVX_BLOCKS, 256, 0, stream>>>(
            part, fill, sorted, W, Wb, x, xb);
        moe_gemm_sp<<<GRID_WG, 256, 0, stream>>>(xb, Wb, b, fill, sorted, out);
    } else if (ws_size >= slow_bytes) {
        int* sorted = (int*)d_ws;
        int* fill   = sorted + sorted_elems;

        hipMemsetAsync(fill, 0xFF, N_EXPERTS * sizeof(int), stream);
        prep_kernel<<<SCATTER_BLOCKS, 256, 0, stream>>>(
            part, fill, sorted, (const float*)nullptr, (unsigned short*)nullptr,
            x, (unsigned short*)nullptr);
        moe_gemm_f32<<<GEMM_GRID, 256, 0, stream>>>(x, W, b, fill, sorted, out);
    }
}